// Round 2
// baseline (143.709 us; speedup 1.0000x reference)
//
#include <hip/hip_runtime.h>
#include <math.h>

#define NROWS 8192
#define NC 10
#define LOG2E_F 1.4426950408889634f

// ws layout (floats):
//   P    : [N][12]  = {f0..f9, B2, label_bits}        (12N)
//   L10  : [N][10]  = 10*log2(f+1e-45)                (10N)
//   psum : [N]      per-sample L1 values              (N)
//   part : [nchunk][N][11] = {acc0..acc9, den}        (11*nchunk*N)

__global__ __launch_bounds__(256) void kde_prep(const float* __restrict__ logits,
                                                const int* __restrict__ labels,
                                                float* __restrict__ P,
                                                float* __restrict__ L10) {
    int i = blockIdx.x * 256 + threadIdx.x;
    if (i >= NROWS) return;
    float l[NC];
#pragma unroll
    for (int c = 0; c < NC; ++c) l[c] = logits[i * NC + c];
    float m = l[0];
#pragma unroll
    for (int c = 1; c < NC; ++c) m = fmaxf(m, l[c]);
    float e[NC];
    float sum = 0.f;
#pragma unroll
    for (int c = 0; c < NC; ++c) { e[c] = expf(l[c] - m); sum += e[c]; }
    float lg = 0.f;
#pragma unroll
    for (int c = 0; c < NC; ++c) {
        float f = e[c] / sum;
        P[i * 12 + c] = f;
        L10[i * NC + c] = 10.f * log2f(f + 1e-45f);
        lg += lgammaf(fmaf(10.f, f, 1.f));
    }
    // sum(alphas) == 1/h + C == 20 exactly -> lgamma(sum) is a constant
    float b2 = (lg - lgammaf(20.0f)) * LOG2E_F;
    P[i * 12 + 10] = b2;
    P[i * 12 + 11] = __int_as_float(labels[i]);
}

// dot(L10_i, f_j) over 10 classes, row r = {v0.xyzw, v1.xyzw, v2.xy}
#define DOT10(la)                                                              \
    fmaf((la)[9], v2.y,                                                        \
    fmaf((la)[8], v2.x,                                                        \
    fmaf((la)[7], v1.w,                                                        \
    fmaf((la)[6], v1.z,                                                        \
    fmaf((la)[5], v1.y,                                                        \
    fmaf((la)[4], v1.x,                                                        \
    fmaf((la)[3], v0.w,                                                        \
    fmaf((la)[2], v0.z,                                                        \
    fmaf((la)[1], v0.y, (la)[0] * v0.x)))))))))

__global__ __launch_bounds__(256) void kde_main(const float* __restrict__ P,
                                                const float* __restrict__ L10,
                                                float* __restrict__ part,
                                                int nchunk) {
    __shared__ float sP[256 * 12];   // 12 KB: 256 packed j-rows
    const int tid = threadIdx.x;
    const int i0 = blockIdx.x * 1024 + tid;   // 4 i-rows per thread
    const int i1 = i0 + 256;
    const int i2 = i0 + 512;
    const int i3 = i0 + 768;

    float la0[NC], la1[NC], la2[NC], la3[NC];
#pragma unroll
    for (int c = 0; c < NC; ++c) {
        la0[c] = L10[i0 * NC + c];
        la1[c] = L10[i1 * NC + c];
        la2[c] = L10[i2 * NC + c];
        la3[c] = L10[i3 * NC + c];
    }
    float acc0[NC], acc1[NC], acc2[NC], acc3[NC];
#pragma unroll
    for (int c = 0; c < NC; ++c) { acc0[c] = 0.f; acc1[c] = 0.f; acc2[c] = 0.f; acc3[c] = 0.f; }
    float den0 = 0.f, den1 = 0.f, den2 = 0.f, den3 = 0.f;

    const int jsz = NROWS / nchunk;
    const int jbeg = blockIdx.y * jsz;
    for (int js = jbeg; js < jbeg + jsz; js += 256) {
        __syncthreads();
#pragma unroll
        for (int t = 0; t < 12; ++t) {
            int idx = t * 256 + tid;
            sP[idx] = P[js * 12 + idx];      // coalesced copy of 256 rows
        }
        __syncthreads();

        for (int jj = 0; jj < 256; ++jj) {
            const float* r = &sP[jj * 12];
            float4 v0 = *(const float4*)(r);       // f0..f3  (LDS broadcast)
            float4 v1 = *(const float4*)(r + 4);   // f4..f7
            float4 v2 = *(const float4*)(r + 8);   // f8, f9, B2, label
            float b2 = v2.z;
            int lab = __builtin_amdgcn_readfirstlane(__float_as_int(v2.w)); // block-uniform
            int j = js + jj;

            float k0 = exp2f(DOT10(la0) - b2);
            float k1 = exp2f(DOT10(la1) - b2);
            float k2 = exp2f(DOT10(la2) - b2);
            float k3 = exp2f(DOT10(la3) - b2);
            k0 = (j == i0) ? 0.f : k0;   // leave-one-out diagonal
            k1 = (j == i1) ? 0.f : k1;
            k2 = (j == i2) ? 0.f : k2;
            k3 = (j == i3) ? 0.f : k3;
            den0 += k0; den1 += k1; den2 += k2; den3 += k3;
            switch (lab) {               // uniform scalar branch, one add per i
#define CASE(c) case c: acc0[c] += k0; acc1[c] += k1; acc2[c] += k2; acc3[c] += k3; break;
                CASE(0) CASE(1) CASE(2) CASE(3) CASE(4)
                CASE(5) CASE(6) CASE(7) CASE(8) CASE(9)
#undef CASE
            }
        }
    }

    const size_t pb = (size_t)blockIdx.y * NROWS;
    float* p0 = &part[(pb + i0) * 11];
    float* p1 = &part[(pb + i1) * 11];
    float* p2 = &part[(pb + i2) * 11];
    float* p3 = &part[(pb + i3) * 11];
#pragma unroll
    for (int c = 0; c < NC; ++c) { p0[c] = acc0[c]; p1[c] = acc1[c]; p2[c] = acc2[c]; p3[c] = acc3[c]; }
    p0[10] = den0; p1[10] = den1; p2[10] = den2; p3[10] = den3;
}

__global__ __launch_bounds__(256) void kde_finish1(const float* __restrict__ part,
                                                   const float* __restrict__ P,
                                                   float* __restrict__ psum,
                                                   int nchunk) {
    int i = blockIdx.x * 256 + threadIdx.x;
    float acc[NC];
    float den = 0.f;
#pragma unroll
    for (int c = 0; c < NC; ++c) acc[c] = 0.f;
    for (int ch = 0; ch < nchunk; ++ch) {
        const float* p = &part[((size_t)ch * NROWS + i) * 11];
#pragma unroll
        for (int c = 0; c < NC; ++c) acc[c] += p[c];
        den += p[10];
    }
    den = fmaxf(den, 1e-10f);   // clip(den, EPS_DEN, None)
    float per = 0.f;
#pragma unroll
    for (int c = 0; c < NC; ++c) per += fabsf(acc[c] / den - P[i * 12 + c]);
    psum[i] = per;
}

__global__ __launch_bounds__(256) void kde_finish2(const float* __restrict__ psum,
                                                   float* __restrict__ out) {
    __shared__ float red[256];
    int t = threadIdx.x;
    float s = 0.f;
    for (int k = t; k < NROWS; k += 256) s += psum[k];
    red[t] = s;
    __syncthreads();
    for (int off = 128; off > 0; off >>= 1) {
        if (t < off) red[t] += red[t + off];
        __syncthreads();
    }
    if (t == 0) out[0] = red[0] * (1.0f / NROWS);
}

extern "C" void kernel_launch(void* const* d_in, const int* in_sizes, int n_in,
                              void* d_out, int out_size, void* d_ws, size_t ws_size,
                              hipStream_t stream) {
    const float* logits = (const float*)d_in[0];
    const int* labels = (const int*)d_in[1];
    float* out = (float*)d_out;
    float* ws = (float*)d_ws;

    float* P = ws;                        // 12N floats
    float* L10 = ws + 12 * NROWS;         // 10N floats
    float* psum = ws + 22 * NROWS;        // N floats
    float* part = ws + 23 * NROWS;        // nchunk * 11N floats

    int nchunk = 32;                      // 8 tiles * 32 chunks = 256 blocks
    while (nchunk > 1 &&
           (size_t)(23 + 11 * nchunk) * NROWS * sizeof(float) > ws_size)
        nchunk >>= 1;

    kde_prep<<<dim3(NROWS / 256), dim3(256), 0, stream>>>(logits, labels, P, L10);
    kde_main<<<dim3(8, nchunk), dim3(256), 0, stream>>>(P, L10, part, nchunk);
    kde_finish1<<<dim3(NROWS / 256), dim3(256), 0, stream>>>(part, P, psum, nchunk);
    kde_finish2<<<dim3(1), dim3(256), 0, stream>>>(psum, out);
}

// Round 3
// 99.263 us; speedup vs baseline: 1.4478x; 1.4478x over previous
//
#include <hip/hip_runtime.h>
#include <math.h>

#define NROWS 8192
#define NC 10
#define LOG2E_F 1.4426950408889634f

typedef float f32x2 __attribute__((ext_vector_type(2)));

#if __has_builtin(__builtin_amdgcn_exp2f)
#define EXP2F(x) __builtin_amdgcn_exp2f(x)
#else
#define EXP2F(x) exp2f(x)
#endif

// ws layout (floats):
//   P    : [N][12]  = {f0..f9, B2, label_bits}            (12N)
//   L10  : [N][10]  = 10*log2(f+1e-45)                    (10N)
//   psum : [N]      per-sample L1 values                  (N)
//   part : [nchunk][11][N] = {acc0..acc9, den} SoA        (11*nchunk*N)

__global__ __launch_bounds__(256) void kde_prep(const float* __restrict__ logits,
                                                const int* __restrict__ labels,
                                                float* __restrict__ P,
                                                float* __restrict__ L10) {
    int i = blockIdx.x * 256 + threadIdx.x;
    if (i >= NROWS) return;
    float l[NC];
#pragma unroll
    for (int c = 0; c < NC; ++c) l[c] = logits[i * NC + c];
    float m = l[0];
#pragma unroll
    for (int c = 1; c < NC; ++c) m = fmaxf(m, l[c]);
    float e[NC];
    float sum = 0.f;
#pragma unroll
    for (int c = 0; c < NC; ++c) { e[c] = expf(l[c] - m); sum += e[c]; }
    float lg = 0.f;
#pragma unroll
    for (int c = 0; c < NC; ++c) {
        float f = e[c] / sum;
        P[i * 12 + c] = f;
        L10[i * NC + c] = 10.f * log2f(f + 1e-45f);
        lg += lgammaf(fmaf(10.f, f, 1.f));
    }
    // sum(alphas) == 1/h + C == 20 exactly -> lgamma(sum) is a constant
    float b2 = (lg - lgammaf(20.0f)) * LOG2E_F;
    P[i * 12 + 10] = b2;
    P[i * 12 + 11] = __int_as_float(labels[i]);
}

// log2-kernel exponent: dot(la, f_j) - b2_j, packed-f32 form.
// MUST be used identically in kde_main and kde_finish1 (self-exclusion
// subtracts a bit-identical value).
__device__ __forceinline__ float kern_exponent(const f32x2 la[5],
                                               float4 v0, float4 v1, float4 v2) {
    f32x2 q0 = {v0.x, v0.y}, q1 = {v0.z, v0.w};
    f32x2 q2 = {v1.x, v1.y}, q3 = {v1.z, v1.w};
    f32x2 q4 = {v2.x, v2.y};
    f32x2 cA = __builtin_elementwise_fma(la[0], q0,
               __builtin_elementwise_fma(la[2], q2, la[4] * q4));
    f32x2 cB = __builtin_elementwise_fma(la[1], q1, la[3] * q3);
    f32x2 cS = cA + cB;
    return cS.x + cS.y - v2.z;
}

__global__ __launch_bounds__(256) void kde_main(const float* __restrict__ P,
                                                const float* __restrict__ L10,
                                                float* __restrict__ part,
                                                int nchunk) {
    __shared__ float sP[256 * 12];   // 12 KB: 256 packed j-rows
    const int tid = threadIdx.x;
    const int i = blockIdx.x * 256 + tid;   // 1 i-row per thread

    f32x2 la[5];
#pragma unroll
    for (int c = 0; c < 5; ++c)
        la[c] = *(const f32x2*)&L10[i * NC + 2 * c];

    float acc[NC];
#pragma unroll
    for (int c = 0; c < NC; ++c) acc[c] = 0.f;
    float den = 0.f;

    const int jsz = NROWS / nchunk;
    const int jbeg = blockIdx.y * jsz;
    for (int js = jbeg; js < jbeg + jsz; js += 256) {
        __syncthreads();
        const float4* gsrc = (const float4*)(P + (size_t)js * 12);
        float4* ldst = (float4*)sP;
#pragma unroll
        for (int t = 0; t < 3; ++t) {
            int idx = t * 256 + tid;        // 768 float4 = 256 rows x 12 floats
            ldst[idx] = gsrc[idx];
        }
        __syncthreads();

        for (int jj = 0; jj < 256; ++jj) {
            const float* r = &sP[jj * 12];
            float4 v0 = *(const float4*)(r);       // f0..f3  (LDS broadcast)
            float4 v1 = *(const float4*)(r + 4);   // f4..f7
            float4 v2 = *(const float4*)(r + 8);   // f8, f9, B2, label
            int lab = __builtin_amdgcn_readfirstlane(__float_as_int(v2.w));
            float k = EXP2F(kern_exponent(la, v0, v1, v2));  // includes j==i
            den += k;
            switch (lab) {   // block-uniform scalar branch, one v_add per pair
#define CASE(c) case c: acc[c] += k; break;
                CASE(0) CASE(1) CASE(2) CASE(3) CASE(4)
                CASE(5) CASE(6) CASE(7) CASE(8) CASE(9)
#undef CASE
            }
        }
    }

    // SoA: part[(chunk*11 + c)*N + i] — coalesced write and read
    float* pb = part + (size_t)blockIdx.y * 11 * NROWS + i;
#pragma unroll
    for (int c = 0; c < NC; ++c) pb[(size_t)c * NROWS] = acc[c];
    pb[(size_t)10 * NROWS] = den;
}

__global__ __launch_bounds__(256) void kde_finish1(const float* __restrict__ part,
                                                   const float* __restrict__ P,
                                                   const float* __restrict__ L10,
                                                   float* __restrict__ psum,
                                                   int nchunk) {
    int i = blockIdx.x * 256 + threadIdx.x;
    float acc[NC];
    float den = 0.f;
#pragma unroll
    for (int c = 0; c < NC; ++c) acc[c] = 0.f;
    for (int ch = 0; ch < nchunk; ++ch) {
        const float* pb = part + (size_t)ch * 11 * NROWS + i;
#pragma unroll
        for (int c = 0; c < NC; ++c) acc[c] += pb[(size_t)c * NROWS];
        den += pb[(size_t)10 * NROWS];
    }

    // subtract self-kernel kern[i][i] (leave-one-out), bit-identical eval
    f32x2 la[5];
#pragma unroll
    for (int c = 0; c < 5; ++c)
        la[c] = *(const f32x2*)&L10[i * NC + 2 * c];
    float4 v0 = *(const float4*)&P[i * 12];
    float4 v1 = *(const float4*)&P[i * 12 + 4];
    float4 v2 = *(const float4*)&P[i * 12 + 8];
    float self = EXP2F(kern_exponent(la, v0, v1, v2));
    int lab = __float_as_int(v2.w);
    den -= self;
    switch (lab) {
#define CASE(c) case c: acc[c] -= self; break;
        CASE(0) CASE(1) CASE(2) CASE(3) CASE(4)
        CASE(5) CASE(6) CASE(7) CASE(8) CASE(9)
#undef CASE
    }

    den = fmaxf(den, 1e-10f);   // clip(den, EPS_DEN, None)
    float per = 0.f;
    const float* f = &P[i * 12];
#pragma unroll
    for (int c = 0; c < NC; ++c) per += fabsf(acc[c] / den - f[c]);
    psum[i] = per;
}

__global__ __launch_bounds__(256) void kde_finish2(const float* __restrict__ psum,
                                                   float* __restrict__ out) {
    __shared__ float red[256];
    int t = threadIdx.x;
    float s = 0.f;
    for (int k = t; k < NROWS; k += 256) s += psum[k];
    red[t] = s;
    __syncthreads();
    for (int off = 128; off > 0; off >>= 1) {
        if (t < off) red[t] += red[t + off];
        __syncthreads();
    }
    if (t == 0) out[0] = red[0] * (1.0f / NROWS);
}

extern "C" void kernel_launch(void* const* d_in, const int* in_sizes, int n_in,
                              void* d_out, int out_size, void* d_ws, size_t ws_size,
                              hipStream_t stream) {
    const float* logits = (const float*)d_in[0];
    const int* labels = (const int*)d_in[1];
    float* out = (float*)d_out;
    float* ws = (float*)d_ws;

    float* P = ws;                        // 12N floats
    float* L10 = ws + 12 * NROWS;         // 10N floats
    float* psum = ws + 22 * NROWS;        // N floats
    float* part = ws + 23 * NROWS;        // nchunk * 11N floats

    int nchunk = 32;                      // 32 i-tiles x 32 chunks = 1024 blocks
    while (nchunk > 1 &&
           (size_t)(23 + 11 * nchunk) * NROWS * sizeof(float) > ws_size)
        nchunk >>= 1;

    kde_prep<<<dim3(NROWS / 256), dim3(256), 0, stream>>>(logits, labels, P, L10);
    kde_main<<<dim3(NROWS / 256, nchunk), dim3(256), 0, stream>>>(P, L10, part, nchunk);
    kde_finish1<<<dim3(NROWS / 256), dim3(256), 0, stream>>>(part, P, L10, psum, nchunk);
    kde_finish2<<<dim3(1), dim3(256), 0, stream>>>(psum, out);
}